// Round 5
// baseline (205.503 us; speedup 1.0000x reference)
//
#include <hip/hip_runtime.h>

#define NCH 30      // channels per cell; pair = 60 floats = 240 B, 16B-aligned
#define TPB 256

typedef float v4f __attribute__((ext_vector_type(4)));
typedef float v2f __attribute__((ext_vector_type(2)));

__device__ __forceinline__ float iou_f(float x1, float y1, float w1, float h1,
                                       float x2, float y2, float w2, float h2) {
    float l1 = x1 - 0.5f * w1, r1 = x1 + 0.5f * w1;
    float t1 = y1 - 0.5f * h1, b1 = y1 + 0.5f * h1;
    float l2 = x2 - 0.5f * w2, r2 = x2 + 0.5f * w2;
    float t2 = y2 - 0.5f * h2, b2 = y2 + 0.5f * h2;
    float in_h = fminf(b1, b2) - fmaxf(t1, t2);
    float in_w = fminf(r1, r2) - fmaxf(l1, l2);
    float inter = (in_h < 0.f || in_w < 0.f) ? 0.f : in_h * in_w;
    float a1 = (b1 - t1) * (r1 - l1);
    float a2 = (b2 - t2) * (r2 - l2);
    return inter / (a1 + a2 - inter);
}

// Per-cell loss terms given register-resident pair data.
// P,L hold 15 float4 = floats [0..59] of the pair; `o` = 0 (cell A) or 30 (cell B).
#define PF(i) (P[(i) >> 2][(i) & 3])
#define LF(i) (L[(i) >> 2][(i) & 3])

__device__ __forceinline__ void cell_terms(const v4f* P, const v4f* L, int o, float mask,
                                           float& v0, float& v1, float& v2,
                                           float& v3, float& v4) {
    const float gx = LF(o + 1), gy = LF(o + 2), gw = LF(o + 3), gh = LF(o + 4);
    const float i1 = iou_f(PF(o + 1), PF(o + 2), PF(o + 3), PF(o + 4), gx, gy, gw, gh);
    const float i2 = iou_f(PF(o + 6), PF(o + 7), PF(o + 8), PF(o + 9), gx, gy, gw, gh);
    const bool best = (i1 >= i2);
    const float sx = best ? PF(o + 1) : PF(o + 6);
    const float sy = best ? PF(o + 2) : PF(o + 7);
    const float sw = best ? PF(o + 3) : PF(o + 8);
    const float sh = best ? PF(o + 4) : PF(o + 9);
    const float imax = best ? i1 : i2;
    const float imin = best ? i2 : i1;

    const float center = 5.f * ((sx - gx) * (sx - gx) + (sy - gy) * (sy - gy));
    const float dw = sqrtf(sw) - sqrtf(gw);
    const float dh = sqrtf(sh) - sqrtf(gh);
    const float wh = 5.f * (dw * dw + dh * dh);

    float cls = 0.f;
#pragma unroll
    for (int c = 10; c < 30; ++c) {
        const float d = PF(o + c) - LF(o + c);
        cls += d * d;
    }

    v0 += center * mask;
    v1 += wh * mask;
    v2 += imax * mask;
    v3 += imin * mask;
    v4 += cls * mask;
}

// One thread per PAIR of cells (240 B, float4-aligned). Skip both-masked-out pairs.
__global__ __launch_bounds__(TPB) void yolo_partial(const float* __restrict__ pred,
                                                    const float* __restrict__ lab,
                                                    float* __restrict__ partial,
                                                    int n_pairs) {
    __shared__ float red[5][TPB / 64];
    const int tid = threadIdx.x;
    const size_t p = (size_t)blockIdx.x * TPB + tid;

    float v0 = 0.f, v1 = 0.f, v2 = 0.f, v3 = 0.f, v4 = 0.f;

    if (p < (size_t)n_pairs) {
        const float* lp = lab + p * (2 * NCH);
        const v2f mA = *(const v2f*)(lp);         // mask A (ch0), gx A
        const v2f mB = *(const v2f*)(lp + NCH);   // mask B, gx B
        const float maskA = mA[0], maskB = mB[0];

        if (maskA != 0.f || maskB != 0.f) {
            const float* pp = pred + p * (2 * NCH);
            v4f P[15], L[15];
#pragma unroll
            for (int k = 0; k < 15; ++k) P[k] = *(const v4f*)(pp + 4 * k);
#pragma unroll
            for (int k = 0; k < 15; ++k) L[k] = *(const v4f*)(lp + 4 * k);

            if (maskA != 0.f) cell_terms(P, L, 0,   maskA, v0, v1, v2, v3, v4);
            if (maskB != 0.f) cell_terms(P, L, NCH, maskB, v0, v1, v2, v3, v4);
        }
    }

    // ---- Wave (64-lane) shuffle reduction ----
#pragma unroll
    for (int off = 32; off > 0; off >>= 1) {
        v0 += __shfl_down(v0, off);
        v1 += __shfl_down(v1, off);
        v2 += __shfl_down(v2, off);
        v3 += __shfl_down(v3, off);
        v4 += __shfl_down(v4, off);
    }

    const int wave = tid >> 6;
    const int lane = tid & 63;
    if (lane == 0) {
        red[0][wave] = v0;
        red[1][wave] = v1;
        red[2][wave] = v2;
        red[3][wave] = v3;
        red[4][wave] = v4;
    }
    __syncthreads();

    if (tid < 5) {
        float s = 0.f;
#pragma unroll
        for (int w = 0; w < TPB / 64; ++w) s += red[tid][w];
        partial[(size_t)blockIdx.x * 5 + tid] = s;
    }
}

// Reduce n_blocks x 5 partials -> out[0..4]. One block.
__global__ __launch_bounds__(256) void final_reduce(const float* __restrict__ partial,
                                                    float* __restrict__ out,
                                                    int n_blocks) {
    __shared__ float red[5][4];
    const int tid = threadIdx.x;
    float v0 = 0.f, v1 = 0.f, v2 = 0.f, v3 = 0.f, v4 = 0.f;
    for (int b = tid; b < n_blocks; b += 256) {
        const float* q = partial + (size_t)b * 5;
        v0 += q[0]; v1 += q[1]; v2 += q[2]; v3 += q[3]; v4 += q[4];
    }
#pragma unroll
    for (int off = 32; off > 0; off >>= 1) {
        v0 += __shfl_down(v0, off);
        v1 += __shfl_down(v1, off);
        v2 += __shfl_down(v2, off);
        v3 += __shfl_down(v3, off);
        v4 += __shfl_down(v4, off);
    }
    const int wave = tid >> 6;
    const int lane = tid & 63;
    if (lane == 0) {
        red[0][wave] = v0;
        red[1][wave] = v1;
        red[2][wave] = v2;
        red[3][wave] = v3;
        red[4][wave] = v4;
    }
    __syncthreads();
    if (tid < 5) {
        float s = 0.f;
#pragma unroll
        for (int w = 0; w < 4; ++w) s += red[tid][w];
        out[tid] = s;
    }
}

extern "C" void kernel_launch(void* const* d_in, const int* in_sizes, int n_in,
                              void* d_out, int out_size, void* d_ws, size_t ws_size,
                              hipStream_t stream) {
    const float* pred = (const float*)d_in[0];
    const float* lab  = (const float*)d_in[1];
    float* out = (float*)d_out;
    float* partial = (float*)d_ws;                 // 1568*5*4 = 31,360 B

    const int n_cells = in_sizes[0] / NCH;         // 802816
    const int n_pairs = n_cells / 2;               // 401408 = 1568 * 256 exactly
    const int grid = (n_pairs + TPB - 1) / TPB;    // 1568

    hipLaunchKernelGGL(yolo_partial, dim3(grid), dim3(TPB), 0, stream,
                       pred, lab, partial, n_pairs);
    hipLaunchKernelGGL(final_reduce, dim3(1), dim3(256), 0, stream,
                       partial, out, grid);
}